// Round 1
// baseline (4032.428 us; speedup 1.0000x reference)
//
#include <hip/hip_runtime.h>

// Chamfer forward: dist0[i] = min_j ||pc0[i]-pc1[j]||^2 ; out = mean(dist0[dist0<=2])
// N = M = 65536, fp32. VALU-bound brute force, LDS-broadcast candidate tiles.

constexpr int TILE = 1024;          // candidates per LDS tile: 12 KB
constexpr int BLOCK = 256;

__global__ __launch_bounds__(BLOCK) void nn_min_kernel(
    const float* __restrict__ pc0, const float* __restrict__ pc1,
    int n1, float* __restrict__ accum /* [0]=sum, [1]=count */) {
  __shared__ float s[3 * TILE];
  const int i = blockIdx.x * BLOCK + threadIdx.x;
  const float px = pc0[3 * i + 0];
  const float py = pc0[3 * i + 1];
  const float pz = pc0[3 * i + 2];
  float best = 3.4e38f;

  for (int t0 = 0; t0 < n1; t0 += TILE) {
    __syncthreads();
    // coalesced cooperative load of 3*TILE contiguous floats
    for (int k = threadIdx.x; k < 3 * TILE; k += BLOCK)
      s[k] = pc1[3 * t0 + k];
    __syncthreads();
#pragma unroll 8
    for (int k = 0; k < TILE; ++k) {
      // all 64 lanes read the same LDS address -> broadcast, conflict-free
      float dx = px - s[3 * k + 0];
      float dy = py - s[3 * k + 1];
      float dz = pz - s[3 * k + 2];
      float d = fmaf(dx, dx, fmaf(dy, dy, dz * dz));
      best = fminf(best, d);
    }
  }

  // masked contribution
  float v = (best <= 2.0f) ? best : 0.0f;
  float c = (best <= 2.0f) ? 1.0f : 0.0f;

  // wave-64 reduction
  for (int off = 32; off > 0; off >>= 1) {
    v += __shfl_down(v, off, 64);
    c += __shfl_down(c, off, 64);
  }

  __shared__ float wsum[BLOCK / 64], wcnt[BLOCK / 64];
  const int wid = threadIdx.x >> 6;
  if ((threadIdx.x & 63) == 0) { wsum[wid] = v; wcnt[wid] = c; }
  __syncthreads();
  if (threadIdx.x == 0) {
    float sS = 0.f, cS = 0.f;
    for (int w = 0; w < BLOCK / 64; ++w) { sS += wsum[w]; cS += wcnt[w]; }
    atomicAdd(&accum[0], sS);
    atomicAdd(&accum[1], cS);
  }
}

__global__ void finalize_kernel(const float* __restrict__ accum,
                                float* __restrict__ out) {
  out[0] = accum[0] / accum[1];
}

extern "C" void kernel_launch(void* const* d_in, const int* in_sizes, int n_in,
                              void* d_out, int out_size, void* d_ws, size_t ws_size,
                              hipStream_t stream) {
  const float* pc0 = (const float*)d_in[0];
  const float* pc1 = (const float*)d_in[1];
  float* out = (float*)d_out;
  float* accum = (float*)d_ws;

  const int n0 = in_sizes[0] / 3;   // 65536
  const int n1 = in_sizes[1] / 3;   // 65536

  // ws is poisoned 0xAA before every launch -> zero the accumulators
  hipMemsetAsync(accum, 0, 2 * sizeof(float), stream);

  nn_min_kernel<<<n0 / BLOCK, BLOCK, 0, stream>>>(pc0, pc1, n1, accum);
  finalize_kernel<<<1, 1, 0, stream>>>(accum, out);
}

// Round 2
// 565.941 us; speedup vs baseline: 7.1252x; 7.1252x over previous
//
#include <hip/hip_runtime.h>

// Chamfer forward: dist0[i] = min_j ||pc0[i]-pc1[j]||^2 ; out = mean(dist0[dist0<=2])
// N = M = 65536, fp32.
// VALU-bound brute force: P=8 points/thread (56 VALU per 1 LDS b128 broadcast),
// S=16 candidate slices for occupancy, bitwise atomicMin combine.

constexpr int TILE  = 1024;   // candidates staged per LDS tile (float4 = 16 KB)
constexpr int BLOCK = 256;
constexpr int P     = 8;      // points per thread
constexpr int S     = 16;     // candidate slices (grid.y)

__global__ __launch_bounds__(BLOCK, 4) void nn_min_kernel(
    const float* __restrict__ pc0, const float* __restrict__ pc1,
    int n1, unsigned int* __restrict__ bests /* [n0] fp32 bits */) {
  __shared__ float4 s[TILE];

  const int t = threadIdx.x;
  const int pointBase = blockIdx.x * (BLOCK * P);
  const int sliceLen  = n1 / S;               // 4096
  const int c0        = blockIdx.y * sliceLen;

  float px[P], py[P], pz[P], best[P];
#pragma unroll
  for (int p = 0; p < P; ++p) {
    const int i = pointBase + p * BLOCK + t;  // coalesced per p
    px[p] = pc0[3 * i + 0];
    py[p] = pc0[3 * i + 1];
    pz[p] = pc0[3 * i + 2];
    best[p] = 3.4e38f;
  }

  for (int t0 = c0; t0 < c0 + sliceLen; t0 += TILE) {
    __syncthreads();
    // stage TILE candidates as padded float4 (coalesced global reads)
#pragma unroll
    for (int j = 0; j < TILE / BLOCK; ++j) {
      const int c = t + j * BLOCK;
      const int g = t0 + c;
      s[c] = make_float4(pc1[3 * g + 0], pc1[3 * g + 1], pc1[3 * g + 2], 0.f);
    }
    __syncthreads();

#pragma unroll 4
    for (int k = 0; k < TILE; ++k) {
      const float4 c = s[k];   // wave-uniform addr -> broadcast, conflict-free
#pragma unroll
      for (int p = 0; p < P; ++p) {
        const float dx = px[p] - c.x;
        const float dy = py[p] - c.y;
        const float dz = pz[p] - c.z;
        const float d  = fmaf(dx, dx, fmaf(dy, dy, dz * dz));
        best[p] = fminf(best[p], d);
      }
    }
  }

  // combine across slices: fp32 bits are order-preserving for non-negative values
#pragma unroll
  for (int p = 0; p < P; ++p) {
    const int i = pointBase + p * BLOCK + t;
    atomicMin(&bests[i], __float_as_uint(best[p]));
  }
}

__global__ __launch_bounds__(BLOCK) void reduce_kernel(
    const unsigned int* __restrict__ bests, int n0,
    float* __restrict__ accum /* [0]=sum, [1]=count */) {
  const int per = n0 / (gridDim.x * BLOCK);   // elements per thread
  float v = 0.f, c = 0.f;
  for (int j = 0; j < per; ++j) {
    const int i = blockIdx.x * (BLOCK * per) + j * BLOCK + threadIdx.x;
    const float d = __uint_as_float(bests[i]);
    if (d <= 2.0f) { v += d; c += 1.0f; }
  }
  for (int off = 32; off > 0; off >>= 1) {
    v += __shfl_down(v, off, 64);
    c += __shfl_down(c, off, 64);
  }
  __shared__ float wsum[BLOCK / 64], wcnt[BLOCK / 64];
  const int wid = threadIdx.x >> 6;
  if ((threadIdx.x & 63) == 0) { wsum[wid] = v; wcnt[wid] = c; }
  __syncthreads();
  if (threadIdx.x == 0) {
    float sS = 0.f, cS = 0.f;
    for (int w = 0; w < BLOCK / 64; ++w) { sS += wsum[w]; cS += wcnt[w]; }
    atomicAdd(&accum[0], sS);
    atomicAdd(&accum[1], cS);
  }
}

__global__ void finalize_kernel(const float* __restrict__ accum,
                                float* __restrict__ out) {
  out[0] = accum[0] / accum[1];
}

extern "C" void kernel_launch(void* const* d_in, const int* in_sizes, int n_in,
                              void* d_out, int out_size, void* d_ws, size_t ws_size,
                              hipStream_t stream) {
  const float* pc0 = (const float*)d_in[0];
  const float* pc1 = (const float*)d_in[1];
  float* out = (float*)d_out;

  const int n0 = in_sizes[0] / 3;   // 65536
  const int n1 = in_sizes[1] / 3;   // 65536

  unsigned int* bests = (unsigned int*)d_ws;          // n0 * 4 bytes
  float* accum = (float*)((char*)d_ws + (size_t)n0 * 4);  // 2 floats

  // init: bests = 0x7F7F7F7F (~3.39e38, > any distance), accum = 0
  hipMemsetAsync(bests, 0x7F, (size_t)n0 * 4, stream);
  hipMemsetAsync(accum, 0, 2 * sizeof(float), stream);

  dim3 grid(n0 / (BLOCK * P), S);
  nn_min_kernel<<<grid, BLOCK, 0, stream>>>(pc0, pc1, n1, bests);
  reduce_kernel<<<64, BLOCK, 0, stream>>>(bests, n0, accum);
  finalize_kernel<<<1, 1, 0, stream>>>(accum, out);
}

// Round 3
// 374.829 us; speedup vs baseline: 10.7580x; 1.5099x over previous
//
#include <hip/hip_runtime.h>

// Chamfer forward: dist0[i] = min_j ||pc0[i]-pc1[j]||^2 ; out = mean(dist0[dist0<=2])
// N = M = 65536, fp32.
// VALU-bound brute force. Transform: m_j = 0.5||c_j||^2 - p.c_j  (precompute
// 0.5||c||^2 into LDS .w; negated point coords in regs) -> 3 fma + min per pair,
// paired candidates for v_min3_f32. d = max(2*min_m + ||p||^2, 0).

constexpr int TILE  = 1024;   // candidates per LDS tile (float4 = 16 KB)
constexpr int BLOCK = 256;
constexpr int P     = 8;      // points per thread
constexpr int S     = 32;     // candidate slices (grid.y)

__global__ __launch_bounds__(BLOCK, 4) void nn_min_kernel(
    const float* __restrict__ pc0, const float* __restrict__ pc1,
    int n1, unsigned int* __restrict__ bests /* [n0] fp32 bits */) {
  __shared__ float4 s[TILE];

  const int t = threadIdx.x;
  const int pointBase = blockIdx.x * (BLOCK * P);
  const int sliceLen  = n1 / S;               // 2048
  const int c0        = blockIdx.y * sliceLen;

  float nx[P], ny[P], nz[P], pn[P], best[P];
#pragma unroll
  for (int p = 0; p < P; ++p) {
    const int i = pointBase + p * BLOCK + t;  // coalesced per p
    const float x = pc0[3 * i + 0];
    const float y = pc0[3 * i + 1];
    const float z = pc0[3 * i + 2];
    nx[p] = -x; ny[p] = -y; nz[p] = -z;
    pn[p] = fmaf(x, x, fmaf(y, y, z * z));    // ||p||^2
    best[p] = 3.4e38f;
  }

  for (int t0 = c0; t0 < c0 + sliceLen; t0 += TILE) {
    __syncthreads();
    // stage 4 candidates per thread: 3 coalesced float4 loads = 12 floats
    {
      const int cbase = 4 * t;                 // candidate idx within tile
      const float4* g = (const float4*)(pc1 + (size_t)3 * (t0 + cbase));
      const float4 a = g[0], b = g[1], c = g[2];
      // unpack 12 floats -> 4 candidates (x,y,z, 0.5*||c||^2)
      s[cbase + 0] = make_float4(a.x, a.y, a.z,
                                 0.5f * fmaf(a.x, a.x, fmaf(a.y, a.y, a.z * a.z)));
      s[cbase + 1] = make_float4(a.w, b.x, b.y,
                                 0.5f * fmaf(a.w, a.w, fmaf(b.x, b.x, b.y * b.y)));
      s[cbase + 2] = make_float4(b.z, b.w, c.x,
                                 0.5f * fmaf(b.z, b.z, fmaf(b.w, b.w, c.x * c.x)));
      s[cbase + 3] = make_float4(c.y, c.z, c.w,
                                 0.5f * fmaf(c.y, c.y, fmaf(c.z, c.z, c.w * c.w)));
    }
    __syncthreads();

#pragma unroll 2
    for (int k = 0; k < TILE; k += 2) {
      const float4 ca = s[k];     // wave-uniform addr -> broadcast
      const float4 cb = s[k + 1];
#pragma unroll
      for (int p = 0; p < P; ++p) {
        const float m0 = fmaf(nx[p], ca.x, fmaf(ny[p], ca.y, fmaf(nz[p], ca.z, ca.w)));
        const float m1 = fmaf(nx[p], cb.x, fmaf(ny[p], cb.y, fmaf(nz[p], cb.z, cb.w)));
        best[p] = fminf(best[p], fminf(m0, m1));   // -> v_min3_f32
      }
    }
  }

  // combine across slices: d = max(2m + ||p||^2, 0) is non-negative -> bitwise min ok
#pragma unroll
  for (int p = 0; p < P; ++p) {
    const int i = pointBase + p * BLOCK + t;
    const float d = fmaxf(fmaf(2.0f, best[p], pn[p]), 0.0f);
    atomicMin(&bests[i], __float_as_uint(d));
  }
}

__global__ __launch_bounds__(BLOCK) void reduce_kernel(
    const unsigned int* __restrict__ bests, int n0,
    float* __restrict__ accum /* [0]=sum, [1]=count */) {
  const int per = n0 / (gridDim.x * BLOCK);   // elements per thread
  float v = 0.f, c = 0.f;
  for (int j = 0; j < per; ++j) {
    const int i = blockIdx.x * (BLOCK * per) + j * BLOCK + threadIdx.x;
    const float d = __uint_as_float(bests[i]);
    if (d <= 2.0f) { v += d; c += 1.0f; }
  }
  for (int off = 32; off > 0; off >>= 1) {
    v += __shfl_down(v, off, 64);
    c += __shfl_down(c, off, 64);
  }
  __shared__ float wsum[BLOCK / 64], wcnt[BLOCK / 64];
  const int wid = threadIdx.x >> 6;
  if ((threadIdx.x & 63) == 0) { wsum[wid] = v; wcnt[wid] = c; }
  __syncthreads();
  if (threadIdx.x == 0) {
    float sS = 0.f, cS = 0.f;
    for (int w = 0; w < BLOCK / 64; ++w) { sS += wsum[w]; cS += wcnt[w]; }
    atomicAdd(&accum[0], sS);
    atomicAdd(&accum[1], cS);
  }
}

__global__ void finalize_kernel(const float* __restrict__ accum,
                                float* __restrict__ out) {
  out[0] = accum[0] / accum[1];
}

extern "C" void kernel_launch(void* const* d_in, const int* in_sizes, int n_in,
                              void* d_out, int out_size, void* d_ws, size_t ws_size,
                              hipStream_t stream) {
  const float* pc0 = (const float*)d_in[0];
  const float* pc1 = (const float*)d_in[1];
  float* out = (float*)d_out;

  const int n0 = in_sizes[0] / 3;   // 65536
  const int n1 = in_sizes[1] / 3;   // 65536

  unsigned int* bests = (unsigned int*)d_ws;              // n0 * 4 bytes
  float* accum = (float*)((char*)d_ws + (size_t)n0 * 4);  // 2 floats

  // init: bests = 0x7F7F7F7F (~3.39e38, > any distance), accum = 0
  hipMemsetAsync(bests, 0x7F, (size_t)n0 * 4, stream);
  hipMemsetAsync(accum, 0, 2 * sizeof(float), stream);

  dim3 grid(n0 / (BLOCK * P), S);
  nn_min_kernel<<<grid, BLOCK, 0, stream>>>(pc0, pc1, n1, bests);
  reduce_kernel<<<64, BLOCK, 0, stream>>>(bests, n0, accum);
  finalize_kernel<<<1, 1, 0, stream>>>(accum, out);
}

// Round 4
// 368.720 us; speedup vs baseline: 10.9363x; 1.0166x over previous
//
#include <hip/hip_runtime.h>

// Chamfer forward: dist0[i] = min_j ||pc0[i]-pc1[j]||^2 ; out = mean(dist0[dist0<=2])
// N = M = 65536, fp32. VALU-bound brute force.
// m_j = 0.5||c_j||^2 - p.c_j (half-norm precomputed into LDS .w) -> 3 fma + min3/2 per pair.
// P=16 points/thread so each broadcast ds_read_b128 feeds 112 VALU ops (LDS pipe ~82us < VALU floor ~191us).
// S=64 slices -> sliceLen == TILE -> single staging round; 1024 blocks = 4/CU.

constexpr int TILE  = 1024;   // candidates per LDS tile (float4 = 16 KB)
constexpr int BLOCK = 256;
constexpr int P     = 16;     // points per thread
constexpr int S     = 64;     // candidate slices (grid.y)

__global__ __launch_bounds__(BLOCK, 4) void nn_min_kernel(
    const float* __restrict__ pc0, const float* __restrict__ pc1,
    unsigned int* __restrict__ bests /* [n0] fp32 bits */) {
  __shared__ float4 s[TILE];

  const int t = threadIdx.x;
  const int pointBase = blockIdx.x * (BLOCK * P);
  const int c0        = blockIdx.y * TILE;

  // stage TILE candidates: 4 candidates/thread via 3 coalesced float4 loads
  {
    const int cbase = 4 * t;
    const float4* g = (const float4*)(pc1 + (size_t)3 * (c0 + cbase));
    const float4 a = g[0], b = g[1], c = g[2];
    s[cbase + 0] = make_float4(a.x, a.y, a.z,
                               0.5f * fmaf(a.x, a.x, fmaf(a.y, a.y, a.z * a.z)));
    s[cbase + 1] = make_float4(a.w, b.x, b.y,
                               0.5f * fmaf(a.w, a.w, fmaf(b.x, b.x, b.y * b.y)));
    s[cbase + 2] = make_float4(b.z, b.w, c.x,
                               0.5f * fmaf(b.z, b.z, fmaf(b.w, b.w, c.x * c.x)));
    s[cbase + 3] = make_float4(c.y, c.z, c.w,
                               0.5f * fmaf(c.y, c.y, fmaf(c.z, c.z, c.w * c.w)));
  }

  // load P points (negated); ||p||^2 recomputed at the end to save VGPRs
  float nx[P], ny[P], nz[P], best[P];
#pragma unroll
  for (int p = 0; p < P; ++p) {
    const int i = pointBase + p * BLOCK + t;
    nx[p] = -pc0[3 * i + 0];
    ny[p] = -pc0[3 * i + 1];
    nz[p] = -pc0[3 * i + 2];
    best[p] = 3.4e38f;
  }
  __syncthreads();

#pragma unroll 2
  for (int k = 0; k < TILE; k += 2) {
    const float4 ca = s[k];     // wave-uniform addr -> broadcast, conflict-free
    const float4 cb = s[k + 1];
#pragma unroll
    for (int p = 0; p < P; ++p) {
      const float m0 = fmaf(nx[p], ca.x, fmaf(ny[p], ca.y, fmaf(nz[p], ca.z, ca.w)));
      const float m1 = fmaf(nx[p], cb.x, fmaf(ny[p], cb.y, fmaf(nz[p], cb.z, cb.w)));
      best[p] = fminf(best[p], fminf(m0, m1));   // -> v_min3_f32
    }
  }

  // d = max(2m + ||p||^2, 0) >= 0 -> bitwise atomicMin is order-preserving
#pragma unroll
  for (int p = 0; p < P; ++p) {
    const int i = pointBase + p * BLOCK + t;
    const float pn = fmaf(nx[p], nx[p], fmaf(ny[p], ny[p], nz[p] * nz[p]));
    const float d = fmaxf(fmaf(2.0f, best[p], pn), 0.0f);
    atomicMin(&bests[i], __float_as_uint(d));
  }
}

__global__ __launch_bounds__(BLOCK) void reduce_kernel(
    const unsigned int* __restrict__ bests, int n0,
    float* __restrict__ accum /* [0]=sum, [1]=count */) {
  const int per = n0 / (gridDim.x * BLOCK);   // elements per thread
  float v = 0.f, c = 0.f;
  for (int j = 0; j < per; ++j) {
    const int i = blockIdx.x * (BLOCK * per) + j * BLOCK + threadIdx.x;
    const float d = __uint_as_float(bests[i]);
    if (d <= 2.0f) { v += d; c += 1.0f; }
  }
  for (int off = 32; off > 0; off >>= 1) {
    v += __shfl_down(v, off, 64);
    c += __shfl_down(c, off, 64);
  }
  __shared__ float wsum[BLOCK / 64], wcnt[BLOCK / 64];
  const int wid = threadIdx.x >> 6;
  if ((threadIdx.x & 63) == 0) { wsum[wid] = v; wcnt[wid] = c; }
  __syncthreads();
  if (threadIdx.x == 0) {
    float sS = 0.f, cS = 0.f;
    for (int w = 0; w < BLOCK / 64; ++w) { sS += wsum[w]; cS += wcnt[w]; }
    atomicAdd(&accum[0], sS);
    atomicAdd(&accum[1], cS);
  }
}

__global__ void finalize_kernel(const float* __restrict__ accum,
                                float* __restrict__ out) {
  out[0] = accum[0] / accum[1];
}

extern "C" void kernel_launch(void* const* d_in, const int* in_sizes, int n_in,
                              void* d_out, int out_size, void* d_ws, size_t ws_size,
                              hipStream_t stream) {
  const float* pc0 = (const float*)d_in[0];
  const float* pc1 = (const float*)d_in[1];
  float* out = (float*)d_out;

  const int n0 = in_sizes[0] / 3;   // 65536
  const int n1 = in_sizes[1] / 3;   // 65536
  (void)n1;

  unsigned int* bests = (unsigned int*)d_ws;              // n0 * 4 bytes
  float* accum = (float*)((char*)d_ws + (size_t)n0 * 4);  // 2 floats

  // init: bests = 0x7F7F7F7F (~3.39e38, > any distance), accum = 0
  hipMemsetAsync(bests, 0x7F, (size_t)n0 * 4, stream);
  hipMemsetAsync(accum, 0, 2 * sizeof(float), stream);

  dim3 grid(n0 / (BLOCK * P), S);   // 16 x 64 = 1024 blocks
  nn_min_kernel<<<grid, BLOCK, 0, stream>>>(pc0, pc1, bests);
  reduce_kernel<<<64, BLOCK, 0, stream>>>(bests, n0, accum);
  finalize_kernel<<<1, 1, 0, stream>>>(accum, out);
}